// Round 6
// baseline (380.338 us; speedup 1.0000x reference)
//
#include <hip/hip_runtime.h>

typedef _Float16 f16x8 __attribute__((ext_vector_type(8)));
typedef float    f32x4 __attribute__((ext_vector_type(4)));

#define Bq   32
#define Lq   4096
#define Eq   1024
#define ROWS_OUT 2049                 // cache_len + 1
#define TOT_G (Bq * ROWS_OUT)         // 65568 gemm rows = 16 * 4098
#define NTILE (TOT_G / 16)            // 4098 tiles of 16 rows

// ---------------------------------------------------------------------------
// K1: vec[b][e] = inputA[b].W1a[e] + b1a[e] + inputB[b].W1b[e] + b1b[e]
// Wave per e; W rows in registers, loop over b (inputs L1/L2-resident).
// ---------------------------------------------------------------------------
__global__ __launch_bounds__(256) void vec_kernel(
    const float* __restrict__ inA, const float* __restrict__ inB,
    const float* __restrict__ W1a, const float* __restrict__ b1a,
    const float* __restrict__ W1b, const float* __restrict__ b1b,
    float* __restrict__ vec)
{
    int e    = (blockIdx.x * 256 + threadIdx.x) >> 6;
    int lane = threadIdx.x & 63;
    if (e >= Eq) return;

    const float4* wa4 = (const float4*)(W1a + (size_t)e * Eq);
    const float4* wb4 = (const float4*)(W1b + (size_t)e * Eq);
    float4 wa[4], wb[4];
#pragma unroll
    for (int j = 0; j < 4; ++j) { wa[j] = wa4[lane + 64 * j]; wb[j] = wb4[lane + 64 * j]; }
    float bias = b1a[e] + b1b[e];

#pragma unroll 4
    for (int b = 0; b < Bq; ++b) {
        const float4* a4  = (const float4*)(inA + (size_t)b * Eq);
        const float4* bb4 = (const float4*)(inB + (size_t)b * Eq);
        float acc = 0.f;
#pragma unroll
        for (int j = 0; j < 4; ++j) {
            float4 a = a4[lane + 64 * j];
            acc += wa[j].x * a.x + wa[j].y * a.y + wa[j].z * a.z + wa[j].w * a.w;
            float4 v = bb4[lane + 64 * j];
            acc += wb[j].x * v.x + wb[j].y * v.y + wb[j].z * v.z + wb[j].w * v.w;
        }
#pragma unroll
        for (int s = 32; s; s >>= 1) acc += __shfl_xor(acc, s, 64);
        if (lane == 0) vec[(size_t)b * Eq + e] = acc + bias;
    }
}

// ---------------------------------------------------------------------------
// K2: pure streaming copy of rows t in [start_row, L) (proven ~6.5 TB/s).
// ---------------------------------------------------------------------------
__global__ __launch_bounds__(256) void copy_kernel(
    const float* __restrict__ src, float* __restrict__ dst,
    int start_row, int f4_per_b)
{
    int b = blockIdx.y;
    int base = blockIdx.x * 1024 + threadIdx.x;
    size_t rowbase = ((size_t)b * Lq + start_row) * (Eq / 4);
    const float4* s4 = (const float4*)src;
    float4* d4 = (float4*)dst;
#pragma unroll
    for (int j = 0; j < 4; ++j) {
        int r4 = base + j * 256;
        if (r4 < f4_per_b) d4[rowbase + r4] = s4[rowbase + r4];
    }
}

// ---------------------------------------------------------------------------
// K3: barrier-free fused copy+GEMM for rows t in [0, cache_len].
// 256 blocks x 512 threads (8 waves), 128 KB LDS (1 block/CU).
// W2 staged ONCE into LDS in exact B-fragment order (then one __syncthreads,
// the only barrier in the kernel). Each wave independently processes 16-row
// tiles: per K-step s, lane l loads rows directly from global in A-fragment
// layout (row tile*16+(l&15), floats s*32+(l>>4)*8 .. +8 — 16 rows x 128
// contiguous bytes per wave instruction = dense cache lines), stores the f32
// back to ncache (copy, trails loads in vmcnt queue), converts to f16, and
// feeds 4 MFMAs (N-tiles) with B-frags from conflict-free lane-contiguous
// ds_read_b128. No cross-wave data sharing => no barriers => streams at HBM
// rate; MFMA/LDS/VALU all <10% of the memory budget.
// ---------------------------------------------------------------------------
__global__ __launch_bounds__(512, 1) void mm_kernel(
    const float* __restrict__ cache, const float* __restrict__ vec,
    const float* __restrict__ W2, const float* __restrict__ b2,
    float* __restrict__ outp, float* __restrict__ ncache)
{
    __shared__ _Float16 w2lds[64 * Eq];   // 128 KB, fragment-permuted

    const int tid = threadIdx.x;
    const int w = tid >> 6, l = tid & 63;
    const int m = l & 15;          // row-in-tile (A) / out col-in-ntile (D)
    const int kq = l >> 4;         // 0..3: k-subgroup

    // ---- stage W2 -> LDS in B-fragment order (frag (nt,s) at f16x8 index
    // (nt*32+s)*64 + l; lane l holds W2[16nt+m][s*32+kq*8+j], j=0..7) ----
    {
        int nt = w >> 1;
        int s0 = (w & 1) * 16;
        const float* wrow = W2 + (size_t)(16 * nt + m) * Eq;
#pragma unroll
        for (int s = s0; s < s0 + 16; ++s) {
            int c0 = s * 32 + kq * 8;
            float4 x = *(const float4*)(wrow + c0);
            float4 y = *(const float4*)(wrow + c0 + 4);
            f16x8 h;
            h[0] = (_Float16)x.x; h[1] = (_Float16)x.y;
            h[2] = (_Float16)x.z; h[3] = (_Float16)x.w;
            h[4] = (_Float16)y.x; h[5] = (_Float16)y.y;
            h[6] = (_Float16)y.z; h[7] = (_Float16)y.w;
            *(f16x8*)(w2lds + ((size_t)((nt * 32 + s) * 64 + l)) * 8) = h;
        }
    }
    __syncthreads();   // once; hot loop below has NO barriers

    const float bb0 = b2[m], bb1 = b2[16 + m], bb2 = b2[32 + m], bb3 = b2[48 + m];

    const int gw = blockIdx.x * 8 + w;             // 0..2047
    for (int tile = gw; tile < NTILE; tile += 2048) {
        // per-lane source/dest row (tiles may straddle batch boundary)
        int R  = tile * 16 + m;
        int bb = R / ROWS_OUT;
        int t  = R - bb * ROWS_OUT;
        const float* src = (t == ROWS_OUT - 1) ? (vec + (size_t)bb * Eq)
                                               : (cache + ((size_t)bb * Lq + t) * Eq);
        float* dst = ncache + ((size_t)bb * Lq + t) * Eq;
        const int c0 = kq * 8;

        f32x4 acc0 = {0.f,0.f,0.f,0.f}, acc1 = {0.f,0.f,0.f,0.f};
        f32x4 acc2 = {0.f,0.f,0.f,0.f}, acc3 = {0.f,0.f,0.f,0.f};

#pragma unroll 8
        for (int s = 0; s < 32; ++s) {
            float4 x = *(const float4*)(src + s * 32 + c0);
            float4 y = *(const float4*)(src + s * 32 + c0 + 4);
            *(float4*)(dst + s * 32 + c0)     = x;      // fused copy
            *(float4*)(dst + s * 32 + c0 + 4) = y;
            f16x8 a;
            a[0] = (_Float16)x.x; a[1] = (_Float16)x.y;
            a[2] = (_Float16)x.z; a[3] = (_Float16)x.w;
            a[4] = (_Float16)y.x; a[5] = (_Float16)y.y;
            a[6] = (_Float16)y.z; a[7] = (_Float16)y.w;
            const f16x8* bp = (const f16x8*)w2lds + (s * 64 + l);
            acc0 = __builtin_amdgcn_mfma_f32_16x16x32_f16(a, bp[0],        acc0, 0, 0, 0);
            acc1 = __builtin_amdgcn_mfma_f32_16x16x32_f16(a, bp[1 * 2048], acc1, 0, 0, 0);
            acc2 = __builtin_amdgcn_mfma_f32_16x16x32_f16(a, bp[2 * 2048], acc2, 0, 0, 0);
            acc3 = __builtin_amdgcn_mfma_f32_16x16x32_f16(a, bp[3 * 2048], acc3, 0, 0, 0);
        }

        // out store: D row = (l>>4)*4 + r, col = 16*nt + m
        int Rst = tile * 16 + kq * 4;
#pragma unroll
        for (int r = 0; r < 4; ++r) {
            float* op = outp + (size_t)(Rst + r) * 64 + m;
            op[0]  = acc0[r] + bb0;
            op[16] = acc1[r] + bb1;
            op[32] = acc2[r] + bb2;
            op[48] = acc3[r] + bb3;
        }
    }
}

// ---------------------------------------------------------------------------
extern "C" void kernel_launch(void* const* d_in, const int* in_sizes, int n_in,
                              void* d_out, int out_size, void* d_ws, size_t ws_size,
                              hipStream_t stream)
{
    const float* inA   = (const float*)d_in[0];
    const float* inB   = (const float*)d_in[1];
    const float* cache = (const float*)d_in[2];
    const float* W1a   = (const float*)d_in[3];
    const float* b1a   = (const float*)d_in[4];
    const float* W1b   = (const float*)d_in[5];
    const float* b1b   = (const float*)d_in[6];
    const float* W2    = (const float*)d_in[7];
    const float* b2v   = (const float*)d_in[8];

    float* outp   = (float*)d_out;                   // (B,2049,64) then (B,L,E)
    float* ncache = outp + (size_t)Bq * ROWS_OUT * 64;
    float* vecbuf = (float*)d_ws;                    // 32*1024 f32

    // K1: vec (mm reads it for t == cache_len rows)
    vec_kernel<<<dim3(256), dim3(256), 0, stream>>>(inA, inB, W1a, b1a, W1b, b1b, vecbuf);

    // K2: pure copy of rows t in [2049, 4096)
    int start_row = ROWS_OUT;                        // 2049
    int f4_per_b  = (Lq - start_row) * (Eq / 4);     // 2047*256
    copy_kernel<<<dim3((f4_per_b + 1023) / 1024, Bq), dim3(256), 0, stream>>>(
        cache, ncache, start_row, f4_per_b);

    // K3: barrier-free fused copy+GEMM for rows t in [0, 2048]
    mm_kernel<<<dim3(256), dim3(512), 0, stream>>>(cache, vecbuf, W2, b2v,
                                                   outp, ncache);
}